// Round 13
// baseline (345.485 us; speedup 1.0000x reference)
//
#include <hip/hip_runtime.h>
#include <cstdint>

#define LRELU_SLOPE 0.2f

typedef short bf16x8_t __attribute__((ext_vector_type(8)));
typedef float f32x4_t  __attribute__((ext_vector_type(4)));

__device__ __forceinline__ float bf2f(unsigned int u) { return __uint_as_float(u << 16); }
__device__ __forceinline__ unsigned short f2bf(float f) {
    unsigned int x = __float_as_uint(f);
    return (unsigned short)((x + 0x7fffu + ((x >> 16) & 1u)) >> 16);
}

// h1x row layout (stride 272 uint16 = 544 B, 16B-aligned):
//   [0..7]  : as1[4] as floats (header)
//   [8..263]: 256 bf16 features
#define H1X_STRIDE 272

// ---------------- fused prep: dtype probe, W1/W2 transpose->bf16, small canon->f32,
// zero offs + sync. flags[0]!=0 => edges int32; flags[1]!=0 => floats bf16.
struct PrepDesc { const void* ssrc[6]; float* sdst[6]; int slen[6]; };
__global__ __launch_bounds__(256) void prep_k(const unsigned short* __restrict__ xh,
                                              const int* __restrict__ ei32,
                                              const void* __restrict__ w1raw,
                                              const void* __restrict__ w2raw,
                                              unsigned short* __restrict__ Wt1,
                                              unsigned short* __restrict__ Wt2,
                                              PrepDesc d, int* __restrict__ flags,
                                              int* __restrict__ offs,
                                              int* __restrict__ sync, int N) {
    __shared__ int s_ei, s_cnt;
    if (threadIdx.x == 0) { s_ei = 0; s_cnt = 0; }
    __syncthreads();
    const int t = threadIdx.x;
    int e_or = 0;
#pragma unroll
    for (int j = 0; j < 4; j++) if (ei32[2 * (t * 4 + j) + 1] != 0) e_or = 1;
    if (e_or) atomicOr(&s_ei, 1);
    int c = 0;
#pragma unroll
    for (int j = 0; j < 8; j++) {
        unsigned short h = xh[t * 8 + j];
        int e = (h >> 7) & 0xFF;
        if (e >= 117 && e < 134) c++;
    }
    atomicAdd(&s_cnt, c);
    __syncthreads();
    const int isb = (s_cnt >= 1600) ? 1 : 0;
    if (blockIdx.x == 0 && t == 0) { flags[0] = s_ei; flags[1] = isb; }
    const int gstride = gridDim.x * blockDim.x;
    const int gid = blockIdx.x * blockDim.x + t;
    for (int i = gid; i < 128 * 256; i += gstride) {       // W1T
        int k = i >> 8, n = i & 255;
        unsigned short b = isb ? ((const unsigned short*)w1raw)[i] : f2bf(((const float*)w1raw)[i]);
        Wt1[n * 128 + k] = b;
    }
    for (int i = gid; i < 256 * 64; i += gstride) {        // W2T
        int k = i >> 6, n = i & 63;
        unsigned short b = isb ? ((const unsigned short*)w2raw)[i] : f2bf(((const float*)w2raw)[i]);
        Wt2[n * 256 + k] = b;
    }
#pragma unroll
    for (int s = 0; s < 6; s++)
        for (int i = gid; i < d.slen[s]; i += gstride) {
            float v = isb ? bf2f((unsigned int)((const unsigned short*)d.ssrc[s])[i])
                          : ((const float*)d.ssrc[s])[i];
            d.sdst[s][i] = v;
        }
    for (int i = gid; i <= N; i += gstride) offs[i] = 0;
    for (int i = gid; i < 1024; i += gstride) sync[i] = 0;
}

// ---------------- standalone histogram (full-width; atomic tail latency overlaps
// across ~13k waves instead of serializing against MFMA work — R12 lesson)
__global__ void hist_k(const int* __restrict__ ei, int E, int N,
                       const int* __restrict__ flags, int* __restrict__ deg) {
    int i = blockIdx.x * blockDim.x + threadIdx.x;
    int T = E + N;
    if (i >= T) return;
    int is64 = (flags[0] == 0);
    int d;
    if (i < E) { long k = (long)E + i; d = is64 ? ei[2 * k] : ei[k]; }
    else d = i - E;
    if ((unsigned)d < (unsigned)N) atomicAdd(&deg[d], 1);
}

// ---------------- GEMM1 via MFMA + fused alpha1. Writes interleaved h1x rows.
__global__ __launch_bounds__(256) void gemm1_k(const void* __restrict__ xraw,
                                               const unsigned short* __restrict__ Wt,
                                               const float* __restrict__ asw_,
                                               const float* __restrict__ adw_,
                                               unsigned short* __restrict__ h1x,
                                               float* __restrict__ ad_,
                                               int M, const int* __restrict__ flags) {
    __shared__ unsigned short xs[64 * 136];
    const int tid = threadIdx.x;
    const long row0 = (long)blockIdx.x * 64;
    if (flags[1] != 0) {
        const uint4* xv = (const uint4*)xraw;
        const long base = row0 * 16;
        const long lim = (long)M * 16 - base;
#pragma unroll
        for (int i = 0; i < 4; i++) {
            int idx = tid + i * 256;
            uint4 v;
            if (idx < lim) v = xv[base + idx];
            else { v.x = v.y = v.z = v.w = 0u; }
            int r = idx >> 4, c8 = idx & 15;
            *(uint4*)&xs[r * 136 + c8 * 8] = v;
        }
    } else {
        const float4* xv = (const float4*)xraw;
        const long base = row0 * 32;
        const long lim = (long)M * 32 - base;
#pragma unroll
        for (int i = 0; i < 8; i++) {
            int idx = tid + i * 256;
            float4 v;
            if (idx < lim) v = xv[base + idx];
            else { v.x = v.y = v.z = v.w = 0.f; }
            int r = idx >> 5, c4 = idx & 31;
            ushort4 o;
            o.x = f2bf(v.x); o.y = f2bf(v.y); o.z = f2bf(v.z); o.w = f2bf(v.w);
            *(ushort4*)&xs[r * 136 + c4 * 4] = o;
        }
    }
    __syncthreads();
    const int wv = tid >> 6;
    const int lane = tid & 63;
    const int l16 = lane & 15, quad = lane >> 4;
    bf16x8_t af[4];
#pragma unroll
    for (int ks = 0; ks < 4; ks++)
        af[ks] = *(const bf16x8_t*)&xs[(wv * 16 + l16) * 136 + ks * 32 + quad * 8];
    float psA[4] = {0.f, 0.f, 0.f, 0.f}, pdA[4] = {0.f, 0.f, 0.f, 0.f};
#pragma unroll
    for (int t = 0; t < 16; t++) {
        f32x4_t acc = {0.f, 0.f, 0.f, 0.f};
#pragma unroll
        for (int ks = 0; ks < 4; ks++) {
            bf16x8_t bf = *(const bf16x8_t*)(Wt + (size_t)(t * 16 + l16) * 128 + ks * 32 + quad * 8);
            acc = __builtin_amdgcn_mfma_f32_16x16x32_bf16(af[ks], bf, acc, 0, 0, 0);
        }
        const float aswv = asw_[t * 16 + l16];
        const float adwv = adw_[t * 16 + l16];
#pragma unroll
        for (int r = 0; r < 4; r++) {
            long grow = row0 + wv * 16 + quad * 4 + r;
            if (grow < M) h1x[grow * H1X_STRIDE + 8 + t * 16 + l16] = f2bf(acc[r]);
            psA[r] = fmaf(acc[r], aswv, psA[r]);
            pdA[r] = fmaf(acc[r], adwv, pdA[r]);
        }
        if ((t & 3) == 3) {
            const int hd = t >> 2;
#pragma unroll
            for (int r = 0; r < 4; r++) {
                float ps = psA[r], pd = pdA[r];
#pragma unroll
                for (int o = 8; o > 0; o >>= 1) {
                    ps += __shfl_down(ps, o, 16);
                    pd += __shfl_down(pd, o, 16);
                }
                long grow = row0 + wv * 16 + quad * 4 + r;
                if (l16 == 0 && grow < M) {
                    ((float*)(h1x + grow * H1X_STRIDE))[hd] = ps;   // header
                    ad_[grow * 4 + hd] = pd;
                }
                psA[r] = 0.f; pdA[r] = 0.f;
            }
        }
    }
}

// ---------------- GEMM2 via MFMA + fused alpha2
__global__ __launch_bounds__(256) void gemm2_k(const unsigned short* __restrict__ x,
                                               const unsigned short* __restrict__ Wt,
                                               const float* __restrict__ asw_,
                                               const float* __restrict__ adw_,
                                               unsigned short* __restrict__ h,
                                               float* __restrict__ as_, float* __restrict__ ad_,
                                               int M) {
    __shared__ unsigned short xs[64 * 264];
    const int tid = threadIdx.x;
    const long row0 = (long)blockIdx.x * 64;
    const uint4* xv = (const uint4*)x;
    const long base = row0 * 32;
    const long lim = (long)M * 32 - base;
#pragma unroll
    for (int i = 0; i < 8; i++) {
        int idx = tid + i * 256;
        uint4 v;
        if (idx < lim) v = xv[base + idx];
        else { v.x = v.y = v.z = v.w = 0u; }
        int r = idx >> 5, c8 = idx & 31;
        *(uint4*)&xs[r * 264 + c8 * 8] = v;
    }
    __syncthreads();
    const int wv = tid >> 6;
    const int lane = tid & 63;
    const int l16 = lane & 15, quad = lane >> 4;
    bf16x8_t af[8];
#pragma unroll
    for (int ks = 0; ks < 8; ks++)
        af[ks] = *(const bf16x8_t*)&xs[(wv * 16 + l16) * 264 + ks * 32 + quad * 8];
    float psA[4] = {0.f, 0.f, 0.f, 0.f}, pdA[4] = {0.f, 0.f, 0.f, 0.f};
#pragma unroll
    for (int t = 0; t < 4; t++) {
        f32x4_t acc = {0.f, 0.f, 0.f, 0.f};
#pragma unroll
        for (int ks = 0; ks < 8; ks++) {
            bf16x8_t bf = *(const bf16x8_t*)(Wt + (size_t)(t * 16 + l16) * 256 + ks * 32 + quad * 8);
            acc = __builtin_amdgcn_mfma_f32_16x16x32_bf16(af[ks], bf, acc, 0, 0, 0);
        }
        const float aswv = asw_[t * 16 + l16];
        const float adwv = adw_[t * 16 + l16];
#pragma unroll
        for (int r = 0; r < 4; r++) {
            long grow = row0 + wv * 16 + quad * 4 + r;
            if (grow < M) h[grow * 64 + t * 16 + l16] = f2bf(acc[r]);
            psA[r] = fmaf(acc[r], aswv, psA[r]);
            pdA[r] = fmaf(acc[r], adwv, pdA[r]);
        }
    }
#pragma unroll
    for (int r = 0; r < 4; r++) {
        float ps = psA[r], pd = pdA[r];
#pragma unroll
        for (int o = 8; o > 0; o >>= 1) { ps += __shfl_down(ps, o, 16); pd += __shfl_down(pd, o, 16); }
        long grow = row0 + wv * 16 + quad * 4 + r;
        if (l16 == 0 && grow < M) { as_[grow] = ps; ad_[grow] = pd; }
    }
}

// ---------------- single-dispatch scan (R9/R12-validated)
__global__ __launch_bounds__(1024) void scan_k(int* __restrict__ offs, int* __restrict__ cursor,
                                               int* __restrict__ sync, int N, int T, int NB) {
    __shared__ int tmp[2][1024];
    __shared__ int carry_s;
    const int tid = threadIdx.x;
    const int b = blockIdx.x;
    const int i = b * 1024 + tid;
    int v = (i < N) ? offs[i] : 0;
    tmp[0][tid] = v;
    __syncthreads();
    int val = v, pb = 0;
    for (int off = 1; off < 1024; off <<= 1) {
        int t = (tid >= off) ? tmp[pb][tid - off] : 0;
        tmp[pb ^ 1][tid] = val + t;
        val += t;
        __syncthreads();
        pb ^= 1;
    }
    const int lexcl = val - v;
    if (tid == 1023) { sync[512 + b] = val; __threadfence(); atomicExch(&sync[b], 1); }
    if (tid < 64) {
        int myv = 0;
        if (tid < NB) {
            while (atomicAdd(&sync[tid], 0) == 0) {}
            myv = atomicAdd(&sync[512 + tid], 0);
        }
        int incl = myv;
#pragma unroll
        for (int o = 1; o < 64; o <<= 1) {
            int t = __shfl_up(incl, o, 64);
            if (tid >= o) incl += t;
        }
        int carry = (b == 0) ? 0 : __shfl(incl, b - 1, 64);
        if (tid == 0) {
            carry_s = carry;
            if (b == 0) offs[N] = T;
        }
    }
    __syncthreads();
    if (i < N) { int o = lexcl + carry_s; offs[i] = o; cursor[i] = o; }
}

// ---------------- slim CSR scatter (esrc only)
__global__ void scat_k(const int* __restrict__ ei, int E, int N,
                       const int* __restrict__ flags, int* __restrict__ cursor,
                       int* __restrict__ esrc) {
    int i = blockIdx.x * blockDim.x + threadIdx.x;
    int T = E + N;
    if (i >= T) return;
    int is64 = (flags[0] == 0);
    int s, d;
    if (i < E) {
        s = is64 ? ei[2 * (long)i] : ei[i];
        long k = (long)E + i;
        d = is64 ? ei[2 * k] : ei[k];
    } else { s = d = i - E; }
    if ((unsigned)d >= (unsigned)N) return;
    if ((unsigned)s >= (unsigned)N) s = 0;
    int pos = atomicAdd(&cursor[d], 1);
    esrc[pos] = s;
}

// ---------------- layer-1 aggregate: interleaved rows (header dword rides the same
// cachelines as the feature gather); inline p = exp(lrelu(as1_h+ad1_h)); unroll 8
__global__ __launch_bounds__(256) void agg1_k(const unsigned short* __restrict__ h1x,
                                              const int* __restrict__ offs,
                                              const int* __restrict__ esrc,
                                              const float* __restrict__ ad_,
                                              const float* __restrict__ bias,
                                              unsigned short* __restrict__ outb, int N) {
    const int wid = threadIdx.x >> 6, lane = threadIdx.x & 63;
    const long node = (long)blockIdx.x * 4 + wid;
    if (node >= N) return;
    const int hh = lane >> 4;
    const float adn = ad_[node * 4 + hh];
    float a0 = 0.f, a1 = 0.f, a2 = 0.f, a3 = 0.f, s = 0.f;
    const int beg = __builtin_amdgcn_readfirstlane(offs[node]);
    const int end = __builtin_amdgcn_readfirstlane(offs[node + 1]);
    int j = beg;
#define LRELU(e) ((e) > 0.f ? (e) : LRELU_SLOPE * (e))
#define EDGE(v, p) { \
        float f0 = bf2f(v.x & 0xffffu), f1 = bf2f(v.x >> 16); \
        float f2 = bf2f(v.y & 0xffffu), f3 = bf2f(v.y >> 16); \
        a0 = fmaf(p, f0, a0); a1 = fmaf(p, f1, a1); \
        a2 = fmaf(p, f2, a2); a3 = fmaf(p, f3, a3); s += p; }
    for (; j + 8 <= end; j += 8) {
        int si[8];
#pragma unroll
        for (int u = 0; u < 8; u++) si[u] = esrc[j + u];
        const unsigned short* rb[8];
#pragma unroll
        for (int u = 0; u < 8; u++) rb[u] = h1x + (long)si[u] * H1X_STRIDE;
        uint2 vv[8];
#pragma unroll
        for (int u = 0; u < 8; u++) vv[u] = *(const uint2*)(rb[u] + 8 + 4 * lane);
        float av[8];
#pragma unroll
        for (int u = 0; u < 8; u++) av[u] = ((const float*)rb[u])[hh];
#pragma unroll
        for (int u = 0; u < 8; u++) {
            const float p = __expf(LRELU(av[u] + adn));
            EDGE(vv[u], p)
        }
    }
    for (; j < end; j++) {
        const int s0 = esrc[j];
        const unsigned short* rb = h1x + (long)s0 * H1X_STRIDE;
        const uint2 v0 = *(const uint2*)(rb + 8 + 4 * lane);
        const float p0 = __expf(LRELU(((const float*)rb)[hh] + adn));
        EDGE(v0, p0)
    }
#undef EDGE
    const float4 bi = ((const float4*)bias)[lane];
    const float inv = 1.f / s;
    uint2 o;
    o.x = (unsigned)f2bf(fmaxf(fmaf(a0, inv, bi.x), 0.f)) |
          ((unsigned)f2bf(fmaxf(fmaf(a1, inv, bi.y), 0.f)) << 16);
    o.y = (unsigned)f2bf(fmaxf(fmaf(a2, inv, bi.z), 0.f)) |
          ((unsigned)f2bf(fmaxf(fmaf(a3, inv, bi.w), 0.f)) << 16);
    ((uint2*)outb)[node * 64 + lane] = o;
}

// ---------------- layer-2 aggregate (H=1): 2 edges per wave-instruction
__global__ __launch_bounds__(256) void agg2_k(const unsigned short* __restrict__ hfeat,
                                              const float* __restrict__ as_,
                                              const float* __restrict__ ad_,
                                              const int* __restrict__ offs,
                                              const int* __restrict__ esrc,
                                              const float* __restrict__ bias,
                                              unsigned short* __restrict__ outb,
                                              float* __restrict__ outf,
                                              const int* __restrict__ flags, int N) {
    const int wid = threadIdx.x >> 6, lane = threadIdx.x & 63;
    const long node = (long)blockIdx.x * 4 + wid;
    if (node >= N) return;
    const int c = lane & 31, eh = lane >> 5;
    const float adn = ad_[node];
    float s = 0.f, acc0 = 0.f, acc1 = 0.f;
    const int beg = __builtin_amdgcn_readfirstlane(offs[node]);
    const int end = __builtin_amdgcn_readfirstlane(offs[node + 1]);
    int j = beg;
#define LRELU(e) ((e) > 0.f ? (e) : LRELU_SLOPE * (e))
    for (; j + 8 <= end; j += 8) {
        int si[4];
#pragma unroll
        for (int u = 0; u < 4; u++) si[u] = esrc[j + 2 * u + eh];
        unsigned int vv[4];
#pragma unroll
        for (int u = 0; u < 4; u++) vv[u] = ((const unsigned int*)(hfeat + (long)si[u] * 64))[c];
        float av[4];
#pragma unroll
        for (int u = 0; u < 4; u++) av[u] = as_[si[u]];
#pragma unroll
        for (int u = 0; u < 4; u++) {
            const float p = __expf(LRELU(av[u] + adn));
            acc0 = fmaf(p, bf2f(vv[u] & 0xffffu), acc0);
            acc1 = fmaf(p, bf2f(vv[u] >> 16), acc1);
            s += p;
        }
    }
    for (; j + 2 <= end; j += 2) {
        const int s0 = esrc[j + eh];
        const unsigned int v = ((const unsigned int*)(hfeat + (long)s0 * 64))[c];
        const float p = __expf(LRELU(as_[s0] + adn));
        acc0 = fmaf(p, bf2f(v & 0xffffu), acc0);
        acc1 = fmaf(p, bf2f(v >> 16), acc1);
        s += p;
    }
    if (j < end && eh == 0) {
        const int s0 = esrc[j];
        const unsigned int v = ((const unsigned int*)(hfeat + (long)s0 * 64))[c];
        const float p = __expf(LRELU(as_[s0] + adn));
        acc0 = fmaf(p, bf2f(v & 0xffffu), acc0);
        acc1 = fmaf(p, bf2f(v >> 16), acc1);
        s += p;
    }
#undef LRELU
    s    += __shfl_xor(s, 32, 64);
    acc0 += __shfl_xor(acc0, 32, 64);
    acc1 += __shfl_xor(acc1, 32, 64);
    if (eh == 0) {
        const float inv = 1.f / s;
        const float v0 = acc0 * inv + bias[2 * c];
        const float v1 = acc1 * inv + bias[2 * c + 1];
        if (flags[1] != 0) {
            unsigned int o = (unsigned)f2bf(v0) | ((unsigned)f2bf(v1) << 16);
            ((unsigned int*)outb)[node * 32 + c] = o;
        } else {
            float2 o; o.x = v0; o.y = v1;
            ((float2*)outf)[node * 32 + c] = o;
        }
    }
}

static inline size_t alignup(size_t v, size_t a) { return (v + a - 1) & ~(a - 1); }

extern "C" void kernel_launch(void* const* d_in, const int* in_sizes, int n_in,
                              void* d_out, int out_size, void* d_ws, size_t ws_size,
                              hipStream_t stream) {
    const void* x  = d_in[0];
    const int*  ei = (const int*)d_in[1];

    const int N = in_sizes[0] / 128;   // 50000
    const int E = in_sizes[1] / 2;     // 800000
    const int T = E + N;
    const int NB = (N + 1023) / 1024;  // 49

    size_t off = 0;
    char* w = (char*)d_ws;
    auto take = [&](size_t bytes) { void* p = w + off; off = alignup(off + bytes, 256); return p; };

    int*   flags = (int*)take(256);
    unsigned short* Wt1 = (unsigned short*)take((size_t)256 * 128 * 2);
    unsigned short* Wt2 = (unsigned short*)take((size_t)64 * 256 * 2);
    float* as1w = (float*)take(256 * 4);
    float* ad1w = (float*)take(256 * 4);
    float* b1f  = (float*)take(256 * 4);
    float* as2w = (float*)take(64 * 4);
    float* ad2w = (float*)take(64 * 4);
    float* b2f  = (float*)take(64 * 4);
    unsigned short* h1x   = (unsigned short*)take((size_t)N * H1X_STRIDE * 2);  // interleaved
    unsigned short* act1b = (unsigned short*)take((size_t)N * 256 * 2);
    float* ad1 = (float*)take((size_t)N * 4 * 4);
    float* as2 = (float*)take((size_t)N * 4);
    float* ad2 = (float*)take((size_t)N * 4);
    int* offs   = (int*)take((size_t)(N + 1) * 4);
    int* cursor = (int*)take((size_t)N * 4);
    int* sync   = (int*)take(1024 * 4);
    int* esrc   = (int*)take((size_t)T * 4);
    unsigned short* h2b = h1x;  // h1x dead after agg1; reuse for layer-2 features

    PrepDesc pd;
    pd.ssrc[0] = d_in[3]; pd.sdst[0] = as1w; pd.slen[0] = 256;
    pd.ssrc[1] = d_in[4]; pd.sdst[1] = ad1w; pd.slen[1] = 256;
    pd.ssrc[2] = d_in[5]; pd.sdst[2] = b1f;  pd.slen[2] = 256;
    pd.ssrc[3] = d_in[7]; pd.sdst[3] = as2w; pd.slen[3] = 64;
    pd.ssrc[4] = d_in[8]; pd.sdst[4] = ad2w; pd.slen[4] = 64;
    pd.ssrc[5] = d_in[9]; pd.sdst[5] = b2f;  pd.slen[5] = 64;
    prep_k<<<64, 256, 0, stream>>>((const unsigned short*)x, ei, d_in[2], d_in[6],
                                   Wt1, Wt2, pd, flags, offs, sync, N);

    hist_k<<<(T + 255) / 256, 256, 0, stream>>>(ei, E, N, flags, offs);
    gemm1_k<<<(N + 63) / 64, 256, 0, stream>>>(x, Wt1, as1w, ad1w, h1x, ad1, N, flags);
    scan_k<<<NB, 1024, 0, stream>>>(offs, cursor, sync, N, T, NB);
    scat_k<<<(T + 255) / 256, 256, 0, stream>>>(ei, E, N, flags, cursor, esrc);
    agg1_k<<<(N + 3) / 4, 256, 0, stream>>>(h1x, offs, esrc, ad1, b1f, act1b, N);
    gemm2_k<<<(N + 63) / 64, 256, 0, stream>>>(act1b, Wt2, as2w, ad2w, h2b, as2, ad2, N);
    agg2_k<<<(N + 3) / 4, 256, 0, stream>>>(h2b, as2, ad2, offs, esrc, b2f,
                                            (unsigned short*)d_out, (float*)d_out, flags, N);
}

// Round 14
// 332.925 us; speedup vs baseline: 1.0377x; 1.0377x over previous
//
#include <hip/hip_runtime.h>
#include <cstdint>

#define LRELU_SLOPE 0.2f

typedef short bf16x8_t __attribute__((ext_vector_type(8)));
typedef float f32x4_t  __attribute__((ext_vector_type(4)));

__device__ __forceinline__ float bf2f(unsigned int u) { return __uint_as_float(u << 16); }
__device__ __forceinline__ unsigned short f2bf(float f) {
    unsigned int x = __float_as_uint(f);
    return (unsigned short)((x + 0x7fffu + ((x >> 16) & 1u)) >> 16);
}

// ---------------- fused prep: dtype probe, W1/W2 transpose->bf16, small canon->f32,
// zero offs + sync. flags[0]!=0 => edges int32; flags[1]!=0 => floats bf16.
struct PrepDesc { const void* ssrc[6]; float* sdst[6]; int slen[6]; };
__global__ __launch_bounds__(256) void prep_k(const unsigned short* __restrict__ xh,
                                              const int* __restrict__ ei32,
                                              const void* __restrict__ w1raw,
                                              const void* __restrict__ w2raw,
                                              unsigned short* __restrict__ Wt1,
                                              unsigned short* __restrict__ Wt2,
                                              PrepDesc d, int* __restrict__ flags,
                                              int* __restrict__ offs,
                                              int* __restrict__ sync, int N) {
    __shared__ int s_ei, s_cnt;
    if (threadIdx.x == 0) { s_ei = 0; s_cnt = 0; }
    __syncthreads();
    const int t = threadIdx.x;
    int e_or = 0;
#pragma unroll
    for (int j = 0; j < 4; j++) if (ei32[2 * (t * 4 + j) + 1] != 0) e_or = 1;
    if (e_or) atomicOr(&s_ei, 1);
    int c = 0;
#pragma unroll
    for (int j = 0; j < 8; j++) {
        unsigned short h = xh[t * 8 + j];
        int e = (h >> 7) & 0xFF;
        if (e >= 117 && e < 134) c++;
    }
    atomicAdd(&s_cnt, c);
    __syncthreads();
    const int isb = (s_cnt >= 1600) ? 1 : 0;
    if (blockIdx.x == 0 && t == 0) { flags[0] = s_ei; flags[1] = isb; }
    const int gstride = gridDim.x * blockDim.x;
    const int gid = blockIdx.x * blockDim.x + t;
    for (int i = gid; i < 128 * 256; i += gstride) {       // W1T
        int k = i >> 8, n = i & 255;
        unsigned short b = isb ? ((const unsigned short*)w1raw)[i] : f2bf(((const float*)w1raw)[i]);
        Wt1[n * 128 + k] = b;
    }
    for (int i = gid; i < 256 * 64; i += gstride) {        // W2T
        int k = i >> 6, n = i & 63;
        unsigned short b = isb ? ((const unsigned short*)w2raw)[i] : f2bf(((const float*)w2raw)[i]);
        Wt2[n * 256 + k] = b;
    }
#pragma unroll
    for (int s = 0; s < 6; s++)
        for (int i = gid; i < d.slen[s]; i += gstride) {
            float v = isb ? bf2f((unsigned int)((const unsigned short*)d.ssrc[s])[i])
                          : ((const float*)d.ssrc[s])[i];
            d.sdst[s][i] = v;
        }
    for (int i = gid; i <= N; i += gstride) offs[i] = 0;
    for (int i = gid; i < 1024; i += gstride) sync[i] = 0;
}

// ---------------- standalone histogram (full-width; atomics overlap across ~13k waves)
__global__ void hist_k(const int* __restrict__ ei, int E, int N,
                       const int* __restrict__ flags, int* __restrict__ deg) {
    int i = blockIdx.x * blockDim.x + threadIdx.x;
    int T = E + N;
    if (i >= T) return;
    int is64 = (flags[0] == 0);
    int d;
    if (i < E) { long k = (long)E + i; d = is64 ? ei[2 * k] : ei[k]; }
    else d = i - E;
    if ((unsigned)d < (unsigned)N) atomicAdd(&deg[d], 1);
}

// ---------------- GEMM1 via MFMA + fused alpha1 (standard 512B h1b rows)
__global__ __launch_bounds__(256) void gemm1_k(const void* __restrict__ xraw,
                                               const unsigned short* __restrict__ Wt,
                                               const float* __restrict__ asw_,
                                               const float* __restrict__ adw_,
                                               unsigned short* __restrict__ h,
                                               float* __restrict__ as_, float* __restrict__ ad_,
                                               int M, const int* __restrict__ flags) {
    __shared__ unsigned short xs[64 * 136];
    const int tid = threadIdx.x;
    const long row0 = (long)blockIdx.x * 64;
    if (flags[1] != 0) {
        const uint4* xv = (const uint4*)xraw;
        const long base = row0 * 16;
        const long lim = (long)M * 16 - base;
#pragma unroll
        for (int i = 0; i < 4; i++) {
            int idx = tid + i * 256;
            uint4 v;
            if (idx < lim) v = xv[base + idx];
            else { v.x = v.y = v.z = v.w = 0u; }
            int r = idx >> 4, c8 = idx & 15;
            *(uint4*)&xs[r * 136 + c8 * 8] = v;
        }
    } else {
        const float4* xv = (const float4*)xraw;
        const long base = row0 * 32;
        const long lim = (long)M * 32 - base;
#pragma unroll
        for (int i = 0; i < 8; i++) {
            int idx = tid + i * 256;
            float4 v;
            if (idx < lim) v = xv[base + idx];
            else { v.x = v.y = v.z = v.w = 0.f; }
            int r = idx >> 5, c4 = idx & 31;
            ushort4 o;
            o.x = f2bf(v.x); o.y = f2bf(v.y); o.z = f2bf(v.z); o.w = f2bf(v.w);
            *(ushort4*)&xs[r * 136 + c4 * 4] = o;
        }
    }
    __syncthreads();
    const int wv = tid >> 6;
    const int lane = tid & 63;
    const int l16 = lane & 15, quad = lane >> 4;
    bf16x8_t af[4];
#pragma unroll
    for (int ks = 0; ks < 4; ks++)
        af[ks] = *(const bf16x8_t*)&xs[(wv * 16 + l16) * 136 + ks * 32 + quad * 8];
    float psA[4] = {0.f, 0.f, 0.f, 0.f}, pdA[4] = {0.f, 0.f, 0.f, 0.f};
#pragma unroll
    for (int t = 0; t < 16; t++) {
        f32x4_t acc = {0.f, 0.f, 0.f, 0.f};
#pragma unroll
        for (int ks = 0; ks < 4; ks++) {
            bf16x8_t bf = *(const bf16x8_t*)(Wt + (size_t)(t * 16 + l16) * 128 + ks * 32 + quad * 8);
            acc = __builtin_amdgcn_mfma_f32_16x16x32_bf16(af[ks], bf, acc, 0, 0, 0);
        }
        const float aswv = asw_[t * 16 + l16];
        const float adwv = adw_[t * 16 + l16];
#pragma unroll
        for (int r = 0; r < 4; r++) {
            long grow = row0 + wv * 16 + quad * 4 + r;
            if (grow < M) h[grow * 256 + t * 16 + l16] = f2bf(acc[r]);
            psA[r] = fmaf(acc[r], aswv, psA[r]);
            pdA[r] = fmaf(acc[r], adwv, pdA[r]);
        }
        if ((t & 3) == 3) {
            const int hd = t >> 2;
#pragma unroll
            for (int r = 0; r < 4; r++) {
                float ps = psA[r], pd = pdA[r];
#pragma unroll
                for (int o = 8; o > 0; o >>= 1) {
                    ps += __shfl_down(ps, o, 16);
                    pd += __shfl_down(pd, o, 16);
                }
                long grow = row0 + wv * 16 + quad * 4 + r;
                if (l16 == 0 && grow < M) { as_[grow * 4 + hd] = ps; ad_[grow * 4 + hd] = pd; }
                psA[r] = 0.f; pdA[r] = 0.f;
            }
        }
    }
}

// ---------------- GEMM2 via MFMA + fused alpha2
__global__ __launch_bounds__(256) void gemm2_k(const unsigned short* __restrict__ x,
                                               const unsigned short* __restrict__ Wt,
                                               const float* __restrict__ asw_,
                                               const float* __restrict__ adw_,
                                               unsigned short* __restrict__ h,
                                               float* __restrict__ as_, float* __restrict__ ad_,
                                               int M) {
    __shared__ unsigned short xs[64 * 264];
    const int tid = threadIdx.x;
    const long row0 = (long)blockIdx.x * 64;
    const uint4* xv = (const uint4*)x;
    const long base = row0 * 32;
    const long lim = (long)M * 32 - base;
#pragma unroll
    for (int i = 0; i < 8; i++) {
        int idx = tid + i * 256;
        uint4 v;
        if (idx < lim) v = xv[base + idx];
        else { v.x = v.y = v.z = v.w = 0u; }
        int r = idx >> 5, c8 = idx & 31;
        *(uint4*)&xs[r * 264 + c8 * 8] = v;
    }
    __syncthreads();
    const int wv = tid >> 6;
    const int lane = tid & 63;
    const int l16 = lane & 15, quad = lane >> 4;
    bf16x8_t af[8];
#pragma unroll
    for (int ks = 0; ks < 8; ks++)
        af[ks] = *(const bf16x8_t*)&xs[(wv * 16 + l16) * 264 + ks * 32 + quad * 8];
    float psA[4] = {0.f, 0.f, 0.f, 0.f}, pdA[4] = {0.f, 0.f, 0.f, 0.f};
#pragma unroll
    for (int t = 0; t < 4; t++) {
        f32x4_t acc = {0.f, 0.f, 0.f, 0.f};
#pragma unroll
        for (int ks = 0; ks < 8; ks++) {
            bf16x8_t bf = *(const bf16x8_t*)(Wt + (size_t)(t * 16 + l16) * 256 + ks * 32 + quad * 8);
            acc = __builtin_amdgcn_mfma_f32_16x16x32_bf16(af[ks], bf, acc, 0, 0, 0);
        }
        const float aswv = asw_[t * 16 + l16];
        const float adwv = adw_[t * 16 + l16];
#pragma unroll
        for (int r = 0; r < 4; r++) {
            long grow = row0 + wv * 16 + quad * 4 + r;
            if (grow < M) h[grow * 64 + t * 16 + l16] = f2bf(acc[r]);
            psA[r] = fmaf(acc[r], aswv, psA[r]);
            pdA[r] = fmaf(acc[r], adwv, pdA[r]);
        }
    }
#pragma unroll
    for (int r = 0; r < 4; r++) {
        float ps = psA[r], pd = pdA[r];
#pragma unroll
        for (int o = 8; o > 0; o >>= 1) { ps += __shfl_down(ps, o, 16); pd += __shfl_down(pd, o, 16); }
        long grow = row0 + wv * 16 + quad * 4 + r;
        if (l16 == 0 && grow < M) { as_[grow] = ps; ad_[grow] = pd; }
    }
}

// ---------------- single-dispatch scan (R12/R13-validated)
__global__ __launch_bounds__(1024) void scan_k(int* __restrict__ offs, int* __restrict__ cursor,
                                               int* __restrict__ sync, int N, int T, int NB) {
    __shared__ int tmp[2][1024];
    __shared__ int carry_s;
    const int tid = threadIdx.x;
    const int b = blockIdx.x;
    const int i = b * 1024 + tid;
    int v = (i < N) ? offs[i] : 0;
    tmp[0][tid] = v;
    __syncthreads();
    int val = v, pb = 0;
    for (int off = 1; off < 1024; off <<= 1) {
        int t = (tid >= off) ? tmp[pb][tid - off] : 0;
        tmp[pb ^ 1][tid] = val + t;
        val += t;
        __syncthreads();
        pb ^= 1;
    }
    const int lexcl = val - v;
    if (tid == 1023) { sync[512 + b] = val; __threadfence(); atomicExch(&sync[b], 1); }
    if (tid < 64) {
        int myv = 0;
        if (tid < NB) {
            while (atomicAdd(&sync[tid], 0) == 0) {}
            myv = atomicAdd(&sync[512 + tid], 0);
        }
        int incl = myv;
#pragma unroll
        for (int o = 1; o < 64; o <<= 1) {
            int t = __shfl_up(incl, o, 64);
            if (tid >= o) incl += t;
        }
        int carry = (b == 0) ? 0 : __shfl(incl, b - 1, 64);
        if (tid == 0) {
            carry_s = carry;
            if (b == 0) offs[N] = T;
        }
    }
    __syncthreads();
    if (i < N) { int o = lexcl + carry_s; offs[i] = o; cursor[i] = o; }
}

// ---------------- CSR scatter + per-edge softmax numerators (R11-validated)
__global__ void scat_p_k(const int* __restrict__ ei, int E, int N,
                         const int* __restrict__ flags, int* __restrict__ cursor,
                         int* __restrict__ esrc, float4* __restrict__ pw,
                         const float* __restrict__ as1, const float* __restrict__ ad1) {
    int i = blockIdx.x * blockDim.x + threadIdx.x;
    int T = E + N;
    if (i >= T) return;
    int is64 = (flags[0] == 0);
    int s, d;
    if (i < E) {
        s = is64 ? ei[2 * (long)i] : ei[i];
        long k = (long)E + i;
        d = is64 ? ei[2 * k] : ei[k];
    } else { s = d = i - E; }
    if ((unsigned)d >= (unsigned)N) return;
    if ((unsigned)s >= (unsigned)N) s = 0;
    int pos = atomicAdd(&cursor[d], 1);
    esrc[pos] = s;
    float4 a = ((const float4*)as1)[s];
    float4 b = ((const float4*)ad1)[d];
    float e0 = a.x + b.x, e1 = a.y + b.y, e2 = a.z + b.z, e3 = a.w + b.w;
    e0 = e0 > 0.f ? e0 : LRELU_SLOPE * e0;
    e1 = e1 > 0.f ? e1 : LRELU_SLOPE * e1;
    e2 = e2 > 0.f ? e2 : LRELU_SLOPE * e2;
    e3 = e3 > 0.f ? e3 : LRELU_SLOPE * e3;
    float4 p; p.x = __expf(e0); p.y = __expf(e1); p.z = __expf(e2); p.w = __expf(e3);
    pw[pos] = p;
}

// ---------------- layer-1 aggregate (R8/R11 measured-best form): lane -> cols 4i..4i+3,
// uint2 gather, sequential pw stream, unroll 8
__global__ __launch_bounds__(256) void agg1_k(const uint2* __restrict__ hfeat,
                                              const int* __restrict__ offs,
                                              const int* __restrict__ esrc,
                                              const float4* __restrict__ pw,
                                              const float* __restrict__ bias,
                                              unsigned short* __restrict__ outb, int N) {
    const int wid = threadIdx.x >> 6, lane = threadIdx.x & 63;
    const long node = (long)blockIdx.x * 4 + wid;
    if (node >= N) return;
    const int hh = lane >> 4;
    const bool lo = hh < 2, evn = (hh & 1) == 0;
    float a0 = 0.f, a1 = 0.f, a2 = 0.f, a3 = 0.f, s = 0.f;
    const int beg = __builtin_amdgcn_readfirstlane(offs[node]);
    const int end = __builtin_amdgcn_readfirstlane(offs[node + 1]);
    int j = beg;
#define P_SEL(P) (lo ? (evn ? P.x : P.y) : (evn ? P.z : P.w))
#define EDGE(v, p) { \
        float f0 = bf2f(v.x & 0xffffu), f1 = bf2f(v.x >> 16); \
        float f2 = bf2f(v.y & 0xffffu), f3 = bf2f(v.y >> 16); \
        a0 = fmaf(p, f0, a0); a1 = fmaf(p, f1, a1); \
        a2 = fmaf(p, f2, a2); a3 = fmaf(p, f3, a3); s += p; }
    for (; j + 8 <= end; j += 8) {
        int si[8];
#pragma unroll
        for (int u = 0; u < 8; u++) si[u] = esrc[j + u];
        uint2 vv[8];
#pragma unroll
        for (int u = 0; u < 8; u++) vv[u] = hfeat[(long)si[u] * 64 + lane];
        float4 PP[8];
#pragma unroll
        for (int u = 0; u < 8; u++) PP[u] = pw[j + u];
#pragma unroll
        for (int u = 0; u < 8; u++) { const float p = P_SEL(PP[u]); EDGE(vv[u], p) }
    }
    for (; j < end; j++) {
        const int s0 = esrc[j];
        const uint2 v0 = hfeat[(long)s0 * 64 + lane];
        const float4 P0 = pw[j];
        const float p0 = P_SEL(P0);
        EDGE(v0, p0)
    }
#undef EDGE
    const float4 bi = ((const float4*)bias)[lane];
    const float inv = 1.f / s;
    uint2 o;
    o.x = (unsigned)f2bf(fmaxf(fmaf(a0, inv, bi.x), 0.f)) |
          ((unsigned)f2bf(fmaxf(fmaf(a1, inv, bi.y), 0.f)) << 16);
    o.y = (unsigned)f2bf(fmaxf(fmaf(a2, inv, bi.z), 0.f)) |
          ((unsigned)f2bf(fmaxf(fmaf(a3, inv, bi.w), 0.f)) << 16);
    ((uint2*)outb)[node * 64 + lane] = o;
}

// ---------------- layer-2 aggregate (H=1): 2 edges per wave-instruction (R11-validated)
__global__ __launch_bounds__(256) void agg2_k(const unsigned short* __restrict__ hfeat,
                                              const float* __restrict__ as_,
                                              const float* __restrict__ ad_,
                                              const int* __restrict__ offs,
                                              const int* __restrict__ esrc,
                                              const float* __restrict__ bias,
                                              unsigned short* __restrict__ outb,
                                              float* __restrict__ outf,
                                              const int* __restrict__ flags, int N) {
    const int wid = threadIdx.x >> 6, lane = threadIdx.x & 63;
    const long node = (long)blockIdx.x * 4 + wid;
    if (node >= N) return;
    const int c = lane & 31, eh = lane >> 5;
    const float adn = ad_[node];
    float s = 0.f, acc0 = 0.f, acc1 = 0.f;
    const int beg = __builtin_amdgcn_readfirstlane(offs[node]);
    const int end = __builtin_amdgcn_readfirstlane(offs[node + 1]);
    int j = beg;
#define LRELU(e) ((e) > 0.f ? (e) : LRELU_SLOPE * (e))
    for (; j + 8 <= end; j += 8) {
        int si[4];
#pragma unroll
        for (int u = 0; u < 4; u++) si[u] = esrc[j + 2 * u + eh];
        unsigned int vv[4];
#pragma unroll
        for (int u = 0; u < 4; u++) vv[u] = ((const unsigned int*)(hfeat + (long)si[u] * 64))[c];
        float av[4];
#pragma unroll
        for (int u = 0; u < 4; u++) av[u] = as_[si[u]];
#pragma unroll
        for (int u = 0; u < 4; u++) {
            const float p = __expf(LRELU(av[u] + adn));
            acc0 = fmaf(p, bf2f(vv[u] & 0xffffu), acc0);
            acc1 = fmaf(p, bf2f(vv[u] >> 16), acc1);
            s += p;
        }
    }
    for (; j + 2 <= end; j += 2) {
        const int s0 = esrc[j + eh];
        const unsigned int v = ((const unsigned int*)(hfeat + (long)s0 * 64))[c];
        const float p = __expf(LRELU(as_[s0] + adn));
        acc0 = fmaf(p, bf2f(v & 0xffffu), acc0);
        acc1 = fmaf(p, bf2f(v >> 16), acc1);
        s += p;
    }
    if (j < end && eh == 0) {
        const int s0 = esrc[j];
        const unsigned int v = ((const unsigned int*)(hfeat + (long)s0 * 64))[c];
        const float p = __expf(LRELU(as_[s0] + adn));
        acc0 = fmaf(p, bf2f(v & 0xffffu), acc0);
        acc1 = fmaf(p, bf2f(v >> 16), acc1);
        s += p;
    }
#undef LRELU
    s    += __shfl_xor(s, 32, 64);
    acc0 += __shfl_xor(acc0, 32, 64);
    acc1 += __shfl_xor(acc1, 32, 64);
    if (eh == 0) {
        const float inv = 1.f / s;
        const float v0 = acc0 * inv + bias[2 * c];
        const float v1 = acc1 * inv + bias[2 * c + 1];
        if (flags[1] != 0) {
            unsigned int o = (unsigned)f2bf(v0) | ((unsigned)f2bf(v1) << 16);
            ((unsigned int*)outb)[node * 32 + c] = o;
        } else {
            float2 o; o.x = v0; o.y = v1;
            ((float2*)outf)[node * 32 + c] = o;
        }
    }
}

static inline size_t alignup(size_t v, size_t a) { return (v + a - 1) & ~(a - 1); }

extern "C" void kernel_launch(void* const* d_in, const int* in_sizes, int n_in,
                              void* d_out, int out_size, void* d_ws, size_t ws_size,
                              hipStream_t stream) {
    const void* x  = d_in[0];
    const int*  ei = (const int*)d_in[1];

    const int N = in_sizes[0] / 128;   // 50000
    const int E = in_sizes[1] / 2;     // 800000
    const int T = E + N;
    const int NB = (N + 1023) / 1024;  // 49

    size_t off = 0;
    char* w = (char*)d_ws;
    auto take = [&](size_t bytes) { void* p = w + off; off = alignup(off + bytes, 256); return p; };

    int*   flags = (int*)take(256);
    unsigned short* Wt1 = (unsigned short*)take((size_t)256 * 128 * 2);
    unsigned short* Wt2 = (unsigned short*)take((size_t)64 * 256 * 2);
    float* as1w = (float*)take(256 * 4);
    float* ad1w = (float*)take(256 * 4);
    float* b1f  = (float*)take(256 * 4);
    float* as2w = (float*)take(64 * 4);
    float* ad2w = (float*)take(64 * 4);
    float* b2f  = (float*)take(64 * 4);
    unsigned short* h1b   = (unsigned short*)take((size_t)N * 256 * 2);  // reused as h2b
    unsigned short* act1b = (unsigned short*)take((size_t)N * 256 * 2);
    float* as1 = (float*)take((size_t)N * 4 * 4);
    float* ad1 = (float*)take((size_t)N * 4 * 4);
    float* as2 = (float*)take((size_t)N * 4);
    float* ad2 = (float*)take((size_t)N * 4);
    int* offs   = (int*)take((size_t)(N + 1) * 4);
    int* cursor = (int*)take((size_t)N * 4);
    int* sync   = (int*)take(1024 * 4);
    int* esrc   = (int*)take((size_t)T * 4);
    float4* pw  = (float4*)take((size_t)T * 16);
    unsigned short* h2b = h1b;  // h1b dead after agg1

    PrepDesc pd;
    pd.ssrc[0] = d_in[3]; pd.sdst[0] = as1w; pd.slen[0] = 256;
    pd.ssrc[1] = d_in[4]; pd.sdst[1] = ad1w; pd.slen[1] = 256;
    pd.ssrc[2] = d_in[5]; pd.sdst[2] = b1f;  pd.slen[2] = 256;
    pd.ssrc[3] = d_in[7]; pd.sdst[3] = as2w; pd.slen[3] = 64;
    pd.ssrc[4] = d_in[8]; pd.sdst[4] = ad2w; pd.slen[4] = 64;
    pd.ssrc[5] = d_in[9]; pd.sdst[5] = b2f;  pd.slen[5] = 64;
    prep_k<<<64, 256, 0, stream>>>((const unsigned short*)x, ei, d_in[2], d_in[6],
                                   Wt1, Wt2, pd, flags, offs, sync, N);

    hist_k<<<(T + 255) / 256, 256, 0, stream>>>(ei, E, N, flags, offs);
    gemm1_k<<<(N + 63) / 64, 256, 0, stream>>>(x, Wt1, as1w, ad1w, h1b, as1, ad1, N, flags);
    scan_k<<<NB, 1024, 0, stream>>>(offs, cursor, sync, N, T, NB);
    scat_p_k<<<(T + 255) / 256, 256, 0, stream>>>(ei, E, N, flags, cursor, esrc, pw, as1, ad1);
    agg1_k<<<(N + 3) / 4, 256, 0, stream>>>((const uint2*)h1b, offs, esrc, pw, b1f, act1b, N);
    gemm2_k<<<(N + 63) / 64, 256, 0, stream>>>(act1b, Wt2, as2w, ad2w, h2b, as2, ad2, N);
    agg2_k<<<(N + 3) / 4, 256, 0, stream>>>(h2b, as2, ad2, offs, esrc, b2f,
                                            (unsigned short*)d_out, (float*)d_out, flags, N);
}

// Round 15
// 319.527 us; speedup vs baseline: 1.0812x; 1.0419x over previous
//
#include <hip/hip_runtime.h>
#include <cstdint>

#define LRELU_SLOPE 0.2f

typedef short bf16x8_t __attribute__((ext_vector_type(8)));
typedef float f32x4_t  __attribute__((ext_vector_type(4)));

__device__ __forceinline__ float bf2f(unsigned int u) { return __uint_as_float(u << 16); }
__device__ __forceinline__ unsigned short f2bf(float f) {
    unsigned int x = __float_as_uint(f);
    return (unsigned short)((x + 0x7fffu + ((x >> 16) & 1u)) >> 16);
}

// ---------------- fused prep: dtype probe, W1/W2 transpose->bf16, small canon->f32,
// zero offs + sync. flags[0]!=0 => edges int32; flags[1]!=0 => floats bf16.
struct PrepDesc { const void* ssrc[6]; float* sdst[6]; int slen[6]; };
__global__ __launch_bounds__(256) void prep_k(const unsigned short* __restrict__ xh,
                                              const int* __restrict__ ei32,
                                              const void* __restrict__ w1raw,
                                              const void* __restrict__ w2raw,
                                              unsigned short* __restrict__ Wt1,
                                              unsigned short* __restrict__ Wt2,
                                              PrepDesc d, int* __restrict__ flags,
                                              int* __restrict__ offs,
                                              int* __restrict__ sync, int N) {
    __shared__ int s_ei, s_cnt;
    if (threadIdx.x == 0) { s_ei = 0; s_cnt = 0; }
    __syncthreads();
    const int t = threadIdx.x;
    int e_or = 0;
#pragma unroll
    for (int j = 0; j < 4; j++) if (ei32[2 * (t * 4 + j) + 1] != 0) e_or = 1;
    if (e_or) atomicOr(&s_ei, 1);
    int c = 0;
#pragma unroll
    for (int j = 0; j < 8; j++) {
        unsigned short h = xh[t * 8 + j];
        int e = (h >> 7) & 0xFF;
        if (e >= 117 && e < 134) c++;
    }
    atomicAdd(&s_cnt, c);
    __syncthreads();
    const int isb = (s_cnt >= 1600) ? 1 : 0;
    if (blockIdx.x == 0 && t == 0) { flags[0] = s_ei; flags[1] = isb; }
    const int gstride = gridDim.x * blockDim.x;
    const int gid = blockIdx.x * blockDim.x + t;
    for (int i = gid; i < 128 * 256; i += gstride) {       // W1T
        int k = i >> 8, n = i & 255;
        unsigned short b = isb ? ((const unsigned short*)w1raw)[i] : f2bf(((const float*)w1raw)[i]);
        Wt1[n * 128 + k] = b;
    }
    for (int i = gid; i < 256 * 64; i += gstride) {        // W2T
        int k = i >> 6, n = i & 63;
        unsigned short b = isb ? ((const unsigned short*)w2raw)[i] : f2bf(((const float*)w2raw)[i]);
        Wt2[n * 256 + k] = b;
    }
#pragma unroll
    for (int s = 0; s < 6; s++)
        for (int i = gid; i < d.slen[s]; i += gstride) {
            float v = isb ? bf2f((unsigned int)((const unsigned short*)d.ssrc[s])[i])
                          : ((const float*)d.ssrc[s])[i];
            d.sdst[s][i] = v;
        }
    for (int i = gid; i <= N; i += gstride) offs[i] = 0;
    for (int i = gid; i < 1024; i += gstride) sync[i] = 0;
}

// ---------------- GEMM1 via MFMA + fused alpha1 + HETERO histogram blocks.
// Blocks [0..NG): GEMM (barriered path). Blocks [NG..): histogram only — no
// __syncthreads after atomics, so RMW latency overlaps with co-resident MFMA
// blocks instead of serializing (R12 lesson: never barrier behind fire-and-forget
// atomics inside a compute kernel).
__global__ __launch_bounds__(256) void gemm1_k(const void* __restrict__ xraw,
                                               const unsigned short* __restrict__ Wt,
                                               const float* __restrict__ asw_,
                                               const float* __restrict__ adw_,
                                               unsigned short* __restrict__ h,
                                               float* __restrict__ as_, float* __restrict__ ad_,
                                               const int* __restrict__ ei, int E,
                                               int* __restrict__ offs, int NG,
                                               int M, const int* __restrict__ flags) {
    const int tid = threadIdx.x;
    if (blockIdx.x >= NG) {                      // histogram-only block
        const int T = E + M;
        const int is64 = (flags[0] == 0);
        const int nb = gridDim.x - NG;
        const int gs = nb * 256;
        for (int i = (blockIdx.x - NG) * 256 + tid; i < T; i += gs) {
            int d;
            if (i < E) { long k = (long)E + i; d = is64 ? ei[2 * k] : ei[k]; }
            else d = i - E;
            if ((unsigned)d < (unsigned)M) atomicAdd(&offs[d], 1);
        }
        return;
    }
    __shared__ unsigned short xs[64 * 136];
    const long row0 = (long)blockIdx.x * 64;
    if (flags[1] != 0) {
        const uint4* xv = (const uint4*)xraw;
        const long base = row0 * 16;
        const long lim = (long)M * 16 - base;
#pragma unroll
        for (int i = 0; i < 4; i++) {
            int idx = tid + i * 256;
            uint4 v;
            if (idx < lim) v = xv[base + idx];
            else { v.x = v.y = v.z = v.w = 0u; }
            int r = idx >> 4, c8 = idx & 15;
            *(uint4*)&xs[r * 136 + c8 * 8] = v;
        }
    } else {
        const float4* xv = (const float4*)xraw;
        const long base = row0 * 32;
        const long lim = (long)M * 32 - base;
#pragma unroll
        for (int i = 0; i < 8; i++) {
            int idx = tid + i * 256;
            float4 v;
            if (idx < lim) v = xv[base + idx];
            else { v.x = v.y = v.z = v.w = 0.f; }
            int r = idx >> 5, c4 = idx & 31;
            ushort4 o;
            o.x = f2bf(v.x); o.y = f2bf(v.y); o.z = f2bf(v.z); o.w = f2bf(v.w);
            *(ushort4*)&xs[r * 136 + c4 * 4] = o;
        }
    }
    __syncthreads();
    const int wv = tid >> 6;
    const int lane = tid & 63;
    const int l16 = lane & 15, quad = lane >> 4;
    bf16x8_t af[4];
#pragma unroll
    for (int ks = 0; ks < 4; ks++)
        af[ks] = *(const bf16x8_t*)&xs[(wv * 16 + l16) * 136 + ks * 32 + quad * 8];
    float psA[4] = {0.f, 0.f, 0.f, 0.f}, pdA[4] = {0.f, 0.f, 0.f, 0.f};
#pragma unroll
    for (int t = 0; t < 16; t++) {
        f32x4_t acc = {0.f, 0.f, 0.f, 0.f};
#pragma unroll
        for (int ks = 0; ks < 4; ks++) {
            bf16x8_t bf = *(const bf16x8_t*)(Wt + (size_t)(t * 16 + l16) * 128 + ks * 32 + quad * 8);
            acc = __builtin_amdgcn_mfma_f32_16x16x32_bf16(af[ks], bf, acc, 0, 0, 0);
        }
        const float aswv = asw_[t * 16 + l16];
        const float adwv = adw_[t * 16 + l16];
#pragma unroll
        for (int r = 0; r < 4; r++) {
            long grow = row0 + wv * 16 + quad * 4 + r;
            if (grow < M) h[grow * 256 + t * 16 + l16] = f2bf(acc[r]);
            psA[r] = fmaf(acc[r], aswv, psA[r]);
            pdA[r] = fmaf(acc[r], adwv, pdA[r]);
        }
        if ((t & 3) == 3) {
            const int hd = t >> 2;
#pragma unroll
            for (int r = 0; r < 4; r++) {
                float ps = psA[r], pd = pdA[r];
#pragma unroll
                for (int o = 8; o > 0; o >>= 1) {
                    ps += __shfl_down(ps, o, 16);
                    pd += __shfl_down(pd, o, 16);
                }
                long grow = row0 + wv * 16 + quad * 4 + r;
                if (l16 == 0 && grow < M) { as_[grow * 4 + hd] = ps; ad_[grow * 4 + hd] = pd; }
                psA[r] = 0.f; pdA[r] = 0.f;
            }
        }
    }
}

// ---------------- GEMM2 via MFMA + fused alpha2
__global__ __launch_bounds__(256) void gemm2_k(const unsigned short* __restrict__ x,
                                               const unsigned short* __restrict__ Wt,
                                               const float* __restrict__ asw_,
                                               const float* __restrict__ adw_,
                                               unsigned short* __restrict__ h,
                                               float* __restrict__ as_, float* __restrict__ ad_,
                                               int M) {
    __shared__ unsigned short xs[64 * 264];
    const int tid = threadIdx.x;
    const long row0 = (long)blockIdx.x * 64;
    const uint4* xv = (const uint4*)x;
    const long base = row0 * 32;
    const long lim = (long)M * 32 - base;
#pragma unroll
    for (int i = 0; i < 8; i++) {
        int idx = tid + i * 256;
        uint4 v;
        if (idx < lim) v = xv[base + idx];
        else { v.x = v.y = v.z = v.w = 0u; }
        int r = idx >> 5, c8 = idx & 31;
        *(uint4*)&xs[r * 264 + c8 * 8] = v;
    }
    __syncthreads();
    const int wv = tid >> 6;
    const int lane = tid & 63;
    const int l16 = lane & 15, quad = lane >> 4;
    bf16x8_t af[8];
#pragma unroll
    for (int ks = 0; ks < 8; ks++)
        af[ks] = *(const bf16x8_t*)&xs[(wv * 16 + l16) * 264 + ks * 32 + quad * 8];
    float psA[4] = {0.f, 0.f, 0.f, 0.f}, pdA[4] = {0.f, 0.f, 0.f, 0.f};
#pragma unroll
    for (int t = 0; t < 4; t++) {
        f32x4_t acc = {0.f, 0.f, 0.f, 0.f};
#pragma unroll
        for (int ks = 0; ks < 8; ks++) {
            bf16x8_t bf = *(const bf16x8_t*)(Wt + (size_t)(t * 16 + l16) * 256 + ks * 32 + quad * 8);
            acc = __builtin_amdgcn_mfma_f32_16x16x32_bf16(af[ks], bf, acc, 0, 0, 0);
        }
        const float aswv = asw_[t * 16 + l16];
        const float adwv = adw_[t * 16 + l16];
#pragma unroll
        for (int r = 0; r < 4; r++) {
            long grow = row0 + wv * 16 + quad * 4 + r;
            if (grow < M) h[grow * 64 + t * 16 + l16] = f2bf(acc[r]);
            psA[r] = fmaf(acc[r], aswv, psA[r]);
            pdA[r] = fmaf(acc[r], adwv, pdA[r]);
        }
    }
#pragma unroll
    for (int r = 0; r < 4; r++) {
        float ps = psA[r], pd = pdA[r];
#pragma unroll
        for (int o = 8; o > 0; o >>= 1) { ps += __shfl_down(ps, o, 16); pd += __shfl_down(pd, o, 16); }
        long grow = row0 + wv * 16 + quad * 4 + r;
        if (l16 == 0 && grow < M) { as_[grow] = ps; ad_[grow] = pd; }
    }
}

// ---------------- single-dispatch scan (R12/R13/R14-validated)
__global__ __launch_bounds__(1024) void scan_k(int* __restrict__ offs, int* __restrict__ cursor,
                                               int* __restrict__ sync, int N, int T, int NB) {
    __shared__ int tmp[2][1024];
    __shared__ int carry_s;
    const int tid = threadIdx.x;
    const int b = blockIdx.x;
    const int i = b * 1024 + tid;
    int v = (i < N) ? offs[i] : 0;
    tmp[0][tid] = v;
    __syncthreads();
    int val = v, pb = 0;
    for (int off = 1; off < 1024; off <<= 1) {
        int t = (tid >= off) ? tmp[pb][tid - off] : 0;
        tmp[pb ^ 1][tid] = val + t;
        val += t;
        __syncthreads();
        pb ^= 1;
    }
    const int lexcl = val - v;
    if (tid == 1023) { sync[512 + b] = val; __threadfence(); atomicExch(&sync[b], 1); }
    if (tid < 64) {
        int myv = 0;
        if (tid < NB) {
            while (atomicAdd(&sync[tid], 0) == 0) {}
            myv = atomicAdd(&sync[512 + tid], 0);
        }
        int incl = myv;
#pragma unroll
        for (int o = 1; o < 64; o <<= 1) {
            int t = __shfl_up(incl, o, 64);
            if (tid >= o) incl += t;
        }
        int carry = (b == 0) ? 0 : __shfl(incl, b - 1, 64);
        if (tid == 0) {
            carry_s = carry;
            if (b == 0) offs[N] = T;
        }
    }
    __syncthreads();
    if (i < N) { int o = lexcl + carry_s; offs[i] = o; cursor[i] = o; }
}

// ---------------- CSR scatter + per-edge softmax numerators (R11/R14-validated)
__global__ void scat_p_k(const int* __restrict__ ei, int E, int N,
                         const int* __restrict__ flags, int* __restrict__ cursor,
                         int* __restrict__ esrc, float4* __restrict__ pw,
                         const float* __restrict__ as1, const float* __restrict__ ad1) {
    int i = blockIdx.x * blockDim.x + threadIdx.x;
    int T = E + N;
    if (i >= T) return;
    int is64 = (flags[0] == 0);
    int s, d;
    if (i < E) {
        s = is64 ? ei[2 * (long)i] : ei[i];
        long k = (long)E + i;
        d = is64 ? ei[2 * k] : ei[k];
    } else { s = d = i - E; }
    if ((unsigned)d >= (unsigned)N) return;
    if ((unsigned)s >= (unsigned)N) s = 0;
    int pos = atomicAdd(&cursor[d], 1);
    esrc[pos] = s;
    float4 a = ((const float4*)as1)[s];
    float4 b = ((const float4*)ad1)[d];
    float e0 = a.x + b.x, e1 = a.y + b.y, e2 = a.z + b.z, e3 = a.w + b.w;
    e0 = e0 > 0.f ? e0 : LRELU_SLOPE * e0;
    e1 = e1 > 0.f ? e1 : LRELU_SLOPE * e1;
    e2 = e2 > 0.f ? e2 : LRELU_SLOPE * e2;
    e3 = e3 > 0.f ? e3 : LRELU_SLOPE * e3;
    float4 p; p.x = __expf(e0); p.y = __expf(e1); p.z = __expf(e2); p.w = __expf(e3);
    pw[pos] = p;
}

// ---------------- layer-1 aggregate (R8/R11/R14 measured-best form)
__global__ __launch_bounds__(256) void agg1_k(const uint2* __restrict__ hfeat,
                                              const int* __restrict__ offs,
                                              const int* __restrict__ esrc,
                                              const float4* __restrict__ pw,
                                              const float* __restrict__ bias,
                                              unsigned short* __restrict__ outb, int N) {
    const int wid = threadIdx.x >> 6, lane = threadIdx.x & 63;
    const long node = (long)blockIdx.x * 4 + wid;
    if (node >= N) return;
    const int hh = lane >> 4;
    const bool lo = hh < 2, evn = (hh & 1) == 0;
    float a0 = 0.f, a1 = 0.f, a2 = 0.f, a3 = 0.f, s = 0.f;
    const int beg = __builtin_amdgcn_readfirstlane(offs[node]);
    const int end = __builtin_amdgcn_readfirstlane(offs[node + 1]);
    int j = beg;
#define P_SEL(P) (lo ? (evn ? P.x : P.y) : (evn ? P.z : P.w))
#define EDGE(v, p) { \
        float f0 = bf2f(v.x & 0xffffu), f1 = bf2f(v.x >> 16); \
        float f2 = bf2f(v.y & 0xffffu), f3 = bf2f(v.y >> 16); \
        a0 = fmaf(p, f0, a0); a1 = fmaf(p, f1, a1); \
        a2 = fmaf(p, f2, a2); a3 = fmaf(p, f3, a3); s += p; }
    for (; j + 8 <= end; j += 8) {
        int si[8];
#pragma unroll
        for (int u = 0; u < 8; u++) si[u] = esrc[j + u];
        uint2 vv[8];
#pragma unroll
        for (int u = 0; u < 8; u++) vv[u] = hfeat[(long)si[u] * 64 + lane];
        float4 PP[8];
#pragma unroll
        for (int u = 0; u < 8; u++) PP[u] = pw[j + u];
#pragma unroll
        for (int u = 0; u < 8; u++) { const float p = P_SEL(PP[u]); EDGE(vv[u], p) }
    }
    for (; j < end; j++) {
        const int s0 = esrc[j];
        const uint2 v0 = hfeat[(long)s0 * 64 + lane];
        const float4 P0 = pw[j];
        const float p0 = P_SEL(P0);
        EDGE(v0, p0)
    }
#undef EDGE
    const float4 bi = ((const float4*)bias)[lane];
    const float inv = 1.f / s;
    uint2 o;
    o.x = (unsigned)f2bf(fmaxf(fmaf(a0, inv, bi.x), 0.f)) |
          ((unsigned)f2bf(fmaxf(fmaf(a1, inv, bi.y), 0.f)) << 16);
    o.y = (unsigned)f2bf(fmaxf(fmaf(a2, inv, bi.z), 0.f)) |
          ((unsigned)f2bf(fmaxf(fmaf(a3, inv, bi.w), 0.f)) << 16);
    ((uint2*)outb)[node * 64 + lane] = o;
}

// ---------------- layer-2 aggregate (H=1): 2 edges per wave-instruction (R11/R14-validated)
__global__ __launch_bounds__(256) void agg2_k(const unsigned short* __restrict__ hfeat,
                                              const float* __restrict__ as_,
                                              const float* __restrict__ ad_,
                                              const int* __restrict__ offs,
                                              const int* __restrict__ esrc,
                                              const float* __restrict__ bias,
                                              unsigned short* __restrict__ outb,
                                              float* __restrict__ outf,
                                              const int* __restrict__ flags, int N) {
    const int wid = threadIdx.x >> 6, lane = threadIdx.x & 63;
    const long node = (long)blockIdx.x * 4 + wid;
    if (node >= N) return;
    const int c = lane & 31, eh = lane >> 5;
    const float adn = ad_[node];
    float s = 0.f, acc0 = 0.f, acc1 = 0.f;
    const int beg = __builtin_amdgcn_readfirstlane(offs[node]);
    const int end = __builtin_amdgcn_readfirstlane(offs[node + 1]);
    int j = beg;
#define LRELU(e) ((e) > 0.f ? (e) : LRELU_SLOPE * (e))
    for (; j + 8 <= end; j += 8) {
        int si[4];
#pragma unroll
        for (int u = 0; u < 4; u++) si[u] = esrc[j + 2 * u + eh];
        unsigned int vv[4];
#pragma unroll
        for (int u = 0; u < 4; u++) vv[u] = ((const unsigned int*)(hfeat + (long)si[u] * 64))[c];
        float av[4];
#pragma unroll
        for (int u = 0; u < 4; u++) av[u] = as_[si[u]];
#pragma unroll
        for (int u = 0; u < 4; u++) {
            const float p = __expf(LRELU(av[u] + adn));
            acc0 = fmaf(p, bf2f(vv[u] & 0xffffu), acc0);
            acc1 = fmaf(p, bf2f(vv[u] >> 16), acc1);
            s += p;
        }
    }
    for (; j + 2 <= end; j += 2) {
        const int s0 = esrc[j + eh];
        const unsigned int v = ((const unsigned int*)(hfeat + (long)s0 * 64))[c];
        const float p = __expf(LRELU(as_[s0] + adn));
        acc0 = fmaf(p, bf2f(v & 0xffffu), acc0);
        acc1 = fmaf(p, bf2f(v >> 16), acc1);
        s += p;
    }
    if (j < end && eh == 0) {
        const int s0 = esrc[j];
        const unsigned int v = ((const unsigned int*)(hfeat + (long)s0 * 64))[c];
        const float p = __expf(LRELU(as_[s0] + adn));
        acc0 = fmaf(p, bf2f(v & 0xffffu), acc0);
        acc1 = fmaf(p, bf2f(v >> 16), acc1);
        s += p;
    }
#undef LRELU
    s    += __shfl_xor(s, 32, 64);
    acc0 += __shfl_xor(acc0, 32, 64);
    acc1 += __shfl_xor(acc1, 32, 64);
    if (eh == 0) {
        const float inv = 1.f / s;
        const float v0 = acc0 * inv + bias[2 * c];
        const float v1 = acc1 * inv + bias[2 * c + 1];
        if (flags[1] != 0) {
            unsigned int o = (unsigned)f2bf(v0) | ((unsigned)f2bf(v1) << 16);
            ((unsigned int*)outb)[node * 32 + c] = o;
        } else {
            float2 o; o.x = v0; o.y = v1;
            ((float2*)outf)[node * 32 + c] = o;
        }
    }
}

static inline size_t alignup(size_t v, size_t a) { return (v + a - 1) & ~(a - 1); }

extern "C" void kernel_launch(void* const* d_in, const int* in_sizes, int n_in,
                              void* d_out, int out_size, void* d_ws, size_t ws_size,
                              hipStream_t stream) {
    const void* x  = d_in[0];
    const int*  ei = (const int*)d_in[1];

    const int N = in_sizes[0] / 128;   // 50000
    const int E = in_sizes[1] / 2;     // 800000
    const int T = E + N;
    const int NB = (N + 1023) / 1024;  // 49
    const int NG = (N + 63) / 64;      // 782 GEMM blocks
    const int NH = 768;                // histogram blocks (hetero tail)

    size_t off = 0;
    char* w = (char*)d_ws;
    auto take = [&](size_t bytes) { void* p = w + off; off = alignup(off + bytes, 256); return p; };

    int*   flags = (int*)take(256);
    unsigned short* Wt1 = (unsigned short*)take((size_t)256 * 128 * 2);
    unsigned short* Wt2 = (unsigned short*)take((size_t)64 * 256 * 2);
    float* as1w = (float*)take(256 * 4);
    float* ad1w = (float*)take(256 * 4);
    float* b1f  = (float*)take(256 * 4);
    float* as2w = (float*)take(64 * 4);
    float* ad2w = (float*)take(64 * 4);
    float* b2f  = (float*)take(64 * 4);
    unsigned short* h1b   = (unsigned short*)take((size_t)N * 256 * 2);  // reused as h2b
    unsigned short* act1b = (unsigned short*)take((size_t)N * 256 * 2);
    float* as1 = (float*)take((size_t)N * 4 * 4);
    float* ad1 = (float*)take((size_t)N * 4 * 4);
    float* as2 = (float*)take((size_t)N * 4);
    float* ad2 = (float*)take((size_t)N * 4);
    int* offs   = (int*)take((size_t)(N + 1) * 4);
    int* cursor = (int*)take((size_t)N * 4);
    int* sync   = (int*)take(1024 * 4);
    int* esrc   = (int*)take((size_t)T * 4);
    float4* pw  = (float4*)take((size_t)T * 16);
    unsigned short* h2b = h1b;  // h1b dead after agg1

    PrepDesc pd;
    pd.ssrc[0] = d_in[3]; pd.sdst[0] = as1w; pd.slen[0] = 256;
    pd.ssrc[1] = d_in[4]; pd.sdst[1] = ad1w; pd.slen[1] = 256;
    pd.ssrc[2] = d_in[5]; pd.sdst[2] = b1f;  pd.slen[2] = 256;
    pd.ssrc[3] = d_in[7]; pd.sdst[3] = as2w; pd.slen[3] = 64;
    pd.ssrc[4] = d_in[8]; pd.sdst[4] = ad2w; pd.slen[4] = 64;
    pd.ssrc[5] = d_in[9]; pd.sdst[5] = b2f;  pd.slen[5] = 64;
    prep_k<<<64, 256, 0, stream>>>((const unsigned short*)x, ei, d_in[2], d_in[6],
                                   Wt1, Wt2, pd, flags, offs, sync, N);

    gemm1_k<<<NG + NH, 256, 0, stream>>>(x, Wt1, as1w, ad1w, h1b, as1, ad1,
                                         ei, E, offs, NG, N, flags);
    scan_k<<<NB, 1024, 0, stream>>>(offs, cursor, sync, N, T, NB);
    scat_p_k<<<(T + 255) / 256, 256, 0, stream>>>(ei, E, N, flags, cursor, esrc, pw, as1, ad1);
    agg1_k<<<(N + 3) / 4, 256, 0, stream>>>((const uint2*)h1b, offs, esrc, pw, b1f, act1b, N);
    gemm2_k<<<(N + 63) / 64, 256, 0, stream>>>(act1b, Wt2, as2w, ad2w, h2b, as2, ad2, N);
    agg2_k<<<(N + 3) / 4, 256, 0, stream>>>(h2b, as2, ad2, offs, esrc, b2f,
                                            (unsigned short*)d_out, (float*)d_out, flags, N);
}

// Round 16
// 305.153 us; speedup vs baseline: 1.1322x; 1.0471x over previous
//
#include <hip/hip_runtime.h>
#include <cstdint>

#define LRELU_SLOPE 0.2f
#define ELL_K 48

typedef short bf16x8_t __attribute__((ext_vector_type(8)));
typedef float f32x4_t  __attribute__((ext_vector_type(4)));

__device__ __forceinline__ float bf2f(unsigned int u) { return __uint_as_float(u << 16); }
__device__ __forceinline__ unsigned short f2bf(float f) {
    unsigned int x = __float_as_uint(f);
    return (unsigned short)((x + 0x7fffu + ((x >> 16) & 1u)) >> 16);
}
__device__ __forceinline__ unsigned short f2h(float f) {
    union { unsigned short u; _Float16 h; } cv; cv.h = (_Float16)f; return cv.u;
}
__device__ __forceinline__ float h2f(unsigned short u) {
    union { unsigned short u; _Float16 h; } cv; cv.u = u; return (float)cv.h;
}

// ---------------- fused prep: dtype probe, W1/W2 transpose->bf16, small canon->f32,
// zero deg. flags[0]!=0 => edges int32; flags[1]!=0 => floats bf16.
struct PrepDesc { const void* ssrc[6]; float* sdst[6]; int slen[6]; };
__global__ __launch_bounds__(256) void prep_k(const unsigned short* __restrict__ xh,
                                              const int* __restrict__ ei32,
                                              const void* __restrict__ w1raw,
                                              const void* __restrict__ w2raw,
                                              unsigned short* __restrict__ Wt1,
                                              unsigned short* __restrict__ Wt2,
                                              PrepDesc d, int* __restrict__ flags,
                                              int* __restrict__ deg, int N) {
    __shared__ int s_ei, s_cnt;
    if (threadIdx.x == 0) { s_ei = 0; s_cnt = 0; }
    __syncthreads();
    const int t = threadIdx.x;
    int e_or = 0;
#pragma unroll
    for (int j = 0; j < 4; j++) if (ei32[2 * (t * 4 + j) + 1] != 0) e_or = 1;
    if (e_or) atomicOr(&s_ei, 1);
    int c = 0;
#pragma unroll
    for (int j = 0; j < 8; j++) {
        unsigned short h = xh[t * 8 + j];
        int e = (h >> 7) & 0xFF;
        if (e >= 117 && e < 134) c++;
    }
    atomicAdd(&s_cnt, c);
    __syncthreads();
    const int isb = (s_cnt >= 1600) ? 1 : 0;
    if (blockIdx.x == 0 && t == 0) { flags[0] = s_ei; flags[1] = isb; }
    const int gstride = gridDim.x * blockDim.x;
    const int gid = blockIdx.x * blockDim.x + t;
    for (int i = gid; i < 128 * 256; i += gstride) {       // W1T
        int k = i >> 8, n = i & 255;
        unsigned short b = isb ? ((const unsigned short*)w1raw)[i] : f2bf(((const float*)w1raw)[i]);
        Wt1[n * 128 + k] = b;
    }
    for (int i = gid; i < 256 * 64; i += gstride) {        // W2T
        int k = i >> 6, n = i & 63;
        unsigned short b = isb ? ((const unsigned short*)w2raw)[i] : f2bf(((const float*)w2raw)[i]);
        Wt2[n * 256 + k] = b;
    }
#pragma unroll
    for (int s = 0; s < 6; s++)
        for (int i = gid; i < d.slen[s]; i += gstride) {
            float v = isb ? bf2f((unsigned int)((const unsigned short*)d.ssrc[s])[i])
                          : ((const float*)d.ssrc[s])[i];
            d.sdst[s][i] = v;
        }
    for (int i = gid; i < N; i += gstride) deg[i] = 0;
}

// ---------------- GEMM1 via MFMA + fused alpha1 (clean R14 form)
__global__ __launch_bounds__(256) void gemm1_k(const void* __restrict__ xraw,
                                               const unsigned short* __restrict__ Wt,
                                               const float* __restrict__ asw_,
                                               const float* __restrict__ adw_,
                                               unsigned short* __restrict__ h,
                                               float* __restrict__ as_, float* __restrict__ ad_,
                                               int M, const int* __restrict__ flags) {
    __shared__ unsigned short xs[64 * 136];
    const int tid = threadIdx.x;
    const long row0 = (long)blockIdx.x * 64;
    if (flags[1] != 0) {
        const uint4* xv = (const uint4*)xraw;
        const long base = row0 * 16;
        const long lim = (long)M * 16 - base;
#pragma unroll
        for (int i = 0; i < 4; i++) {
            int idx = tid + i * 256;
            uint4 v;
            if (idx < lim) v = xv[base + idx];
            else { v.x = v.y = v.z = v.w = 0u; }
            int r = idx >> 4, c8 = idx & 15;
            *(uint4*)&xs[r * 136 + c8 * 8] = v;
        }
    } else {
        const float4* xv = (const float4*)xraw;
        const long base = row0 * 32;
        const long lim = (long)M * 32 - base;
#pragma unroll
        for (int i = 0; i < 8; i++) {
            int idx = tid + i * 256;
            float4 v;
            if (idx < lim) v = xv[base + idx];
            else { v.x = v.y = v.z = v.w = 0.f; }
            int r = idx >> 5, c4 = idx & 31;
            ushort4 o;
            o.x = f2bf(v.x); o.y = f2bf(v.y); o.z = f2bf(v.z); o.w = f2bf(v.w);
            *(ushort4*)&xs[r * 136 + c4 * 4] = o;
        }
    }
    __syncthreads();
    const int wv = tid >> 6;
    const int lane = tid & 63;
    const int l16 = lane & 15, quad = lane >> 4;
    bf16x8_t af[4];
#pragma unroll
    for (int ks = 0; ks < 4; ks++)
        af[ks] = *(const bf16x8_t*)&xs[(wv * 16 + l16) * 136 + ks * 32 + quad * 8];
    float psA[4] = {0.f, 0.f, 0.f, 0.f}, pdA[4] = {0.f, 0.f, 0.f, 0.f};
#pragma unroll
    for (int t = 0; t < 16; t++) {
        f32x4_t acc = {0.f, 0.f, 0.f, 0.f};
#pragma unroll
        for (int ks = 0; ks < 4; ks++) {
            bf16x8_t bf = *(const bf16x8_t*)(Wt + (size_t)(t * 16 + l16) * 128 + ks * 32 + quad * 8);
            acc = __builtin_amdgcn_mfma_f32_16x16x32_bf16(af[ks], bf, acc, 0, 0, 0);
        }
        const float aswv = asw_[t * 16 + l16];
        const float adwv = adw_[t * 16 + l16];
#pragma unroll
        for (int r = 0; r < 4; r++) {
            long grow = row0 + wv * 16 + quad * 4 + r;
            if (grow < M) h[grow * 256 + t * 16 + l16] = f2bf(acc[r]);
            psA[r] = fmaf(acc[r], aswv, psA[r]);
            pdA[r] = fmaf(acc[r], adwv, pdA[r]);
        }
        if ((t & 3) == 3) {
            const int hd = t >> 2;
#pragma unroll
            for (int r = 0; r < 4; r++) {
                float ps = psA[r], pd = pdA[r];
#pragma unroll
                for (int o = 8; o > 0; o >>= 1) {
                    ps += __shfl_down(ps, o, 16);
                    pd += __shfl_down(pd, o, 16);
                }
                long grow = row0 + wv * 16 + quad * 4 + r;
                if (l16 == 0 && grow < M) { as_[grow * 4 + hd] = ps; ad_[grow * 4 + hd] = pd; }
                psA[r] = 0.f; pdA[r] = 0.f;
            }
        }
    }
}

// ---------------- ELL build: ONE atomic pass = histogram + rank + scatter + softmax
// numerators. Replaces hist+scan+scat_p (the rank atomic doubles as the count).
__global__ void ell_k(const int* __restrict__ ei, int E, int N,
                      const int* __restrict__ flags, int* __restrict__ deg,
                      int* __restrict__ ell_src, uint2* __restrict__ ell_pw,
                      const float* __restrict__ as1, const float* __restrict__ ad1) {
    int i = blockIdx.x * blockDim.x + threadIdx.x;
    int T = E + N;
    if (i >= T) return;
    int is64 = (flags[0] == 0);
    int s, d;
    if (i < E) {
        s = is64 ? ei[2 * (long)i] : ei[i];
        long k = (long)E + i;
        d = is64 ? ei[2 * k] : ei[k];
    } else { s = d = i - E; }
    if ((unsigned)d >= (unsigned)N) return;
    if ((unsigned)s >= (unsigned)N) s = 0;
    int r = atomicAdd(&deg[d], 1);
    if (r >= ELL_K) return;                    // cosmically unlikely; agg clamps too
    long slot = (long)d * ELL_K + r;
    ell_src[slot] = s;
    float4 a = ((const float4*)as1)[s];
    float4 b = ((const float4*)ad1)[d];
    float e0 = a.x + b.x, e1 = a.y + b.y, e2 = a.z + b.z, e3 = a.w + b.w;
    e0 = e0 > 0.f ? e0 : LRELU_SLOPE * e0;
    e1 = e1 > 0.f ? e1 : LRELU_SLOPE * e1;
    e2 = e2 > 0.f ? e2 : LRELU_SLOPE * e2;
    e3 = e3 > 0.f ? e3 : LRELU_SLOPE * e3;
    uint2 p;
    p.x = (unsigned)f2h(__expf(e0)) | ((unsigned)f2h(__expf(e1)) << 16);
    p.y = (unsigned)f2h(__expf(e2)) | ((unsigned)f2h(__expf(e3)) << 16);
    ell_pw[slot] = p;
}

// ---------------- GEMM2 via MFMA + fused alpha2 (unchanged)
__global__ __launch_bounds__(256) void gemm2_k(const unsigned short* __restrict__ x,
                                               const unsigned short* __restrict__ Wt,
                                               const float* __restrict__ asw_,
                                               const float* __restrict__ adw_,
                                               unsigned short* __restrict__ h,
                                               float* __restrict__ as_, float* __restrict__ ad_,
                                               int M) {
    __shared__ unsigned short xs[64 * 264];
    const int tid = threadIdx.x;
    const long row0 = (long)blockIdx.x * 64;
    const uint4* xv = (const uint4*)x;
    const long base = row0 * 32;
    const long lim = (long)M * 32 - base;
#pragma unroll
    for (int i = 0; i < 8; i++) {
        int idx = tid + i * 256;
        uint4 v;
        if (idx < lim) v = xv[base + idx];
        else { v.x = v.y = v.z = v.w = 0u; }
        int r = idx >> 5, c8 = idx & 31;
        *(uint4*)&xs[r * 264 + c8 * 8] = v;
    }
    __syncthreads();
    const int wv = tid >> 6;
    const int lane = tid & 63;
    const int l16 = lane & 15, quad = lane >> 4;
    bf16x8_t af[8];
#pragma unroll
    for (int ks = 0; ks < 8; ks++)
        af[ks] = *(const bf16x8_t*)&xs[(wv * 16 + l16) * 264 + ks * 32 + quad * 8];
    float psA[4] = {0.f, 0.f, 0.f, 0.f}, pdA[4] = {0.f, 0.f, 0.f, 0.f};
#pragma unroll
    for (int t = 0; t < 4; t++) {
        f32x4_t acc = {0.f, 0.f, 0.f, 0.f};
#pragma unroll
        for (int ks = 0; ks < 8; ks++) {
            bf16x8_t bf = *(const bf16x8_t*)(Wt + (size_t)(t * 16 + l16) * 256 + ks * 32 + quad * 8);
            acc = __builtin_amdgcn_mfma_f32_16x16x32_bf16(af[ks], bf, acc, 0, 0, 0);
        }
        const float aswv = asw_[t * 16 + l16];
        const float adwv = adw_[t * 16 + l16];
#pragma unroll
        for (int r = 0; r < 4; r++) {
            long grow = row0 + wv * 16 + quad * 4 + r;
            if (grow < M) h[grow * 64 + t * 16 + l16] = f2bf(acc[r]);
            psA[r] = fmaf(acc[r], aswv, psA[r]);
            pdA[r] = fmaf(acc[r], adwv, pdA[r]);
        }
    }
#pragma unroll
    for (int r = 0; r < 4; r++) {
        float ps = psA[r], pd = pdA[r];
#pragma unroll
        for (int o = 8; o > 0; o >>= 1) { ps += __shfl_down(ps, o, 16); pd += __shfl_down(pd, o, 16); }
        long grow = row0 + wv * 16 + quad * 4 + r;
        if (l16 == 0 && grow < M) { as_[grow] = ps; ad_[grow] = pd; }
    }
}

// ---------------- layer-1 aggregate: ELL rows (node*K base), f16x4 pw, unroll 8
__global__ __launch_bounds__(256) void agg1_k(const uint2* __restrict__ hfeat,
                                              const int* __restrict__ deg,
                                              const int* __restrict__ ell_src,
                                              const uint2* __restrict__ ell_pw,
                                              const float* __restrict__ bias,
                                              unsigned short* __restrict__ outb, int N) {
    const int wid = threadIdx.x >> 6, lane = threadIdx.x & 63;
    const long node = (long)blockIdx.x * 4 + wid;
    if (node >= N) return;
    const int hh = lane >> 4;
    const bool lo = hh < 2, evn = (hh & 1) == 0;
    float a0 = 0.f, a1 = 0.f, a2 = 0.f, a3 = 0.f, s = 0.f;
    int degn = __builtin_amdgcn_readfirstlane(deg[node]);
    const int cnt = degn < ELL_K ? degn : ELL_K;
    const long beg = node * ELL_K;
    int j = 0;
#define P_SEL(P) h2f((unsigned short)(evn ? ((lo ? P.x : P.y) & 0xffffu) : ((lo ? P.x : P.y) >> 16)))
#define EDGE(v, p) { \
        float f0 = bf2f(v.x & 0xffffu), f1 = bf2f(v.x >> 16); \
        float f2 = bf2f(v.y & 0xffffu), f3 = bf2f(v.y >> 16); \
        a0 = fmaf(p, f0, a0); a1 = fmaf(p, f1, a1); \
        a2 = fmaf(p, f2, a2); a3 = fmaf(p, f3, a3); s += p; }
    for (; j + 8 <= cnt; j += 8) {
        int si[8];
#pragma unroll
        for (int u = 0; u < 8; u++) si[u] = ell_src[beg + j + u];
        uint2 vv[8];
#pragma unroll
        for (int u = 0; u < 8; u++) vv[u] = hfeat[(long)si[u] * 64 + lane];
        uint2 PP[8];
#pragma unroll
        for (int u = 0; u < 8; u++) PP[u] = ell_pw[beg + j + u];
#pragma unroll
        for (int u = 0; u < 8; u++) { const float p = P_SEL(PP[u]); EDGE(vv[u], p) }
    }
    for (; j < cnt; j++) {
        const int s0 = ell_src[beg + j];
        const uint2 v0 = hfeat[(long)s0 * 64 + lane];
        const uint2 P0 = ell_pw[beg + j];
        const float p0 = P_SEL(P0);
        EDGE(v0, p0)
    }
#undef EDGE
    const float4 bi = ((const float4*)bias)[lane];
    const float inv = 1.f / s;
    uint2 o;
    o.x = (unsigned)f2bf(fmaxf(fmaf(a0, inv, bi.x), 0.f)) |
          ((unsigned)f2bf(fmaxf(fmaf(a1, inv, bi.y), 0.f)) << 16);
    o.y = (unsigned)f2bf(fmaxf(fmaf(a2, inv, bi.z), 0.f)) |
          ((unsigned)f2bf(fmaxf(fmaf(a3, inv, bi.w), 0.f)) << 16);
    ((uint2*)outb)[node * 64 + lane] = o;
}

// ---------------- layer-2 aggregate (H=1): ELL rows, 2 edges per wave-instruction
__global__ __launch_bounds__(256) void agg2_k(const unsigned short* __restrict__ hfeat,
                                              const float* __restrict__ as_,
                                              const float* __restrict__ ad_,
                                              const int* __restrict__ deg,
                                              const int* __restrict__ ell_src,
                                              const float* __restrict__ bias,
                                              unsigned short* __restrict__ outb,
                                              float* __restrict__ outf,
                                              const int* __restrict__ flags, int N) {
    const int wid = threadIdx.x >> 6, lane = threadIdx.x & 63;
    const long node = (long)blockIdx.x * 4 + wid;
    if (node >= N) return;
    const int c = lane & 31, eh = lane >> 5;
    const float adn = ad_[node];
    float s = 0.f, acc0 = 0.f, acc1 = 0.f;
    int degn = __builtin_amdgcn_readfirstlane(deg[node]);
    const int cnt = degn < ELL_K ? degn : ELL_K;
    const long beg = node * ELL_K;
    int j = 0;
#define LRELU(e) ((e) > 0.f ? (e) : LRELU_SLOPE * (e))
    for (; j + 8 <= cnt; j += 8) {
        int si[4];
#pragma unroll
        for (int u = 0; u < 4; u++) si[u] = ell_src[beg + j + 2 * u + eh];
        unsigned int vv[4];
#pragma unroll
        for (int u = 0; u < 4; u++) vv[u] = ((const unsigned int*)(hfeat + (long)si[u] * 64))[c];
        float av[4];
#pragma unroll
        for (int u = 0; u < 4; u++) av[u] = as_[si[u]];
#pragma unroll
        for (int u = 0; u < 4; u++) {
            const float p = __expf(LRELU(av[u] + adn));
            acc0 = fmaf(p, bf2f(vv[u] & 0xffffu), acc0);
            acc1 = fmaf(p, bf2f(vv[u] >> 16), acc1);
            s += p;
        }
    }
    for (; j + 2 <= cnt; j += 2) {
        const int s0 = ell_src[beg + j + eh];
        const unsigned int v = ((const unsigned int*)(hfeat + (long)s0 * 64))[c];
        const float p = __expf(LRELU(as_[s0] + adn));
        acc0 = fmaf(p, bf2f(v & 0xffffu), acc0);
        acc1 = fmaf(p, bf2f(v >> 16), acc1);
        s += p;
    }
    if (j < cnt && eh == 0) {
        const int s0 = ell_src[beg + j];
        const unsigned int v = ((const unsigned int*)(hfeat + (long)s0 * 64))[c];
        const float p = __expf(LRELU(as_[s0] + adn));
        acc0 = fmaf(p, bf2f(v & 0xffffu), acc0);
        acc1 = fmaf(p, bf2f(v >> 16), acc1);
        s += p;
    }
#undef LRELU
    s    += __shfl_xor(s, 32, 64);
    acc0 += __shfl_xor(acc0, 32, 64);
    acc1 += __shfl_xor(acc1, 32, 64);
    if (eh == 0) {
        const float inv = 1.f / s;
        const float v0 = acc0 * inv + bias[2 * c];
        const float v1 = acc1 * inv + bias[2 * c + 1];
        if (flags[1] != 0) {
            unsigned int o = (unsigned)f2bf(v0) | ((unsigned)f2bf(v1) << 16);
            ((unsigned int*)outb)[node * 32 + c] = o;
        } else {
            float2 o; o.x = v0; o.y = v1;
            ((float2*)outf)[node * 32 + c] = o;
        }
    }
}

static inline size_t alignup(size_t v, size_t a) { return (v + a - 1) & ~(a - 1); }

extern "C" void kernel_launch(void* const* d_in, const int* in_sizes, int n_in,
                              void* d_out, int out_size, void* d_ws, size_t ws_size,
                              hipStream_t stream) {
    const void* x  = d_in[0];
    const int*  ei = (const int*)d_in[1];

    const int N = in_sizes[0] / 128;   // 50000
    const int E = in_sizes[1] / 2;     // 800000
    const int T = E + N;

    size_t off = 0;
    char* w = (char*)d_ws;
    auto take = [&](size_t bytes) { void* p = w + off; off = alignup(off + bytes, 256); return p; };

    int*   flags = (int*)take(256);
    unsigned short* Wt1 = (unsigned short*)take((size_t)256 * 128 * 2);
    unsigned short* Wt2 = (unsigned short*)take((size_t)64 * 256 * 2);
    float* as1w = (float*)take(256 * 4);
    float* ad1w = (float*)take(256 * 4);
    float* b1f  = (float*)take(256 * 4);
    float* as2w = (float*)take(64 * 4);
    float* ad2w = (float*)take(64 * 4);
    float* b2f  = (float*)take(64 * 4);
    unsigned short* h1b   = (unsigned short*)take((size_t)N * 256 * 2);  // reused as h2b
    unsigned short* act1b = (unsigned short*)take((size_t)N * 256 * 2);
    float* as1 = (float*)take((size_t)N * 4 * 4);
    float* ad1 = (float*)take((size_t)N * 4 * 4);
    float* as2 = (float*)take((size_t)N * 4);
    float* ad2 = (float*)take((size_t)N * 4);
    int* deg   = (int*)take((size_t)N * 4);
    int* ell_src = (int*)take((size_t)N * ELL_K * 4);
    uint2* ell_pw = (uint2*)take((size_t)N * ELL_K * 8);
    unsigned short* h2b = h1b;  // h1b dead after agg1

    PrepDesc pd;
    pd.ssrc[0] = d_in[3]; pd.sdst[0] = as1w; pd.slen[0] = 256;
    pd.ssrc[1] = d_in[4]; pd.sdst[1] = ad1w; pd.slen[1] = 256;
    pd.ssrc[2] = d_in[5]; pd.sdst[2] = b1f;  pd.slen[2] = 256;
    pd.ssrc[3] = d_in[7]; pd.sdst[3] = as2w; pd.slen[3] = 64;
    pd.ssrc[4] = d_in[8]; pd.sdst[4] = ad2w; pd.slen[4] = 64;
    pd.ssrc[5] = d_in[9]; pd.sdst[5] = b2f;  pd.slen[5] = 64;
    prep_k<<<64, 256, 0, stream>>>((const unsigned short*)x, ei, d_in[2], d_in[6],
                                   Wt1, Wt2, pd, flags, deg, N);

    gemm1_k<<<(N + 63) / 64, 256, 0, stream>>>(x, Wt1, as1w, ad1w, h1b, as1, ad1, N, flags);
    ell_k<<<(T + 255) / 256, 256, 0, stream>>>(ei, E, N, flags, deg, ell_src, ell_pw, as1, ad1);
    agg1_k<<<(N + 3) / 4, 256, 0, stream>>>((const uint2*)h1b, deg, ell_src, ell_pw, b1f, act1b, N);
    gemm2_k<<<(N + 63) / 64, 256, 0, stream>>>(act1b, Wt2, as2w, ad2w, h2b, as2, ad2, N);
    agg2_k<<<(N + 3) / 4, 256, 0, stream>>>(h2b, as2, ad2, deg, ell_src, b2f,
                                            (unsigned short*)d_out, (float*)d_out, flags, N);
}